// Round 10
// baseline (115.208 us; speedup 1.0000x reference)
//
#include <hip/hip_runtime.h>

typedef __bf16 bf16_t;
typedef __bf16 bf16x8 __attribute__((ext_vector_type(8)));
typedef float  f32x4  __attribute__((ext_vector_type(4)));

#define Ldim 2048
#define Ddim 256

// Build frag-major (B-operand) bf16 copies of weight and input_weight.
// Frag element ((kt*16+nt)*64 + lane)*8 + j  =  W[k=kt*32+(lane>>4)*8+j][n=nt*16+(lane&15)]
__global__ void swz_kernel(const float* __restrict__ w,
                           const float* __restrict__ win,
                           bf16_t* __restrict__ wsw,
                           bf16_t* __restrict__ winsw) {
    int mat = blockIdx.x >> 3, kt = blockIdx.x & 7;
    const float* src = mat ? win : w;
    bf16_t*      dst = mat ? winsw : wsw;
    int ln = threadIdx.x & 63, g = threadIdx.x >> 6;
    int c = ln & 15, q = ln >> 4;
#pragma unroll
    for (int i = 0; i < 4; ++i) {
        int nt = g + 4 * i;
        bf16x8 v;
#pragma unroll
        for (int j = 0; j < 8; ++j)
            v[j] = (bf16_t)src[(kt * 32 + q * 8 + j) * Ddim + nt * 16 + c];
        *(bf16x8*)&dst[((kt * 16 + nt) * 64 + ln) * 8] = v;
    }
}

#define AU_STRIDE 258   // f32; 4-row step = 1032 B -> 2-way bank alias (free)
#define AU_ROWS   72    // window rows 0..70 used
#define AU_BYTES  (AU_ROWS * AU_STRIDE * 4)   // 74304
#define HBUF_BYTES 65536                      // [2 buf][4 mt][8 kt][1024]
#define LDS_TOTAL (HBUF_BYTES + AU_BYTES)     // 139840 -> 1 block/CU

extern __shared__ char ldsmem[];

// 64-row monolithic tile, 256 blocks = 1 block/CU, (256,1): the 64-row shape
// amortizes barriers (7/CU vs 14/CU for two 32-row blocks), halves per-row
// weight-frag traffic, and cuts phase-1 halo MFMA 1.5x->1.25x. Carries R9's
// cooperative X-staging (mt 0..3 staged, identity-per-lane readback), R8's
// u-register-prefetch + immediate addressing. 512-VGPR budget: no spill at
// ~300 regs. setprio removed (lockstep waves: catalog-null).
__global__ __launch_bounds__(256, 1)
void rnn_kernel(const float* __restrict__ x,
                const float* __restrict__ bias,
                const float* __restrict__ tau,
                const bf16x8* __restrict__ wsw,
                const bf16x8* __restrict__ winsw,
                float* __restrict__ out)
{
    char*  hb  = ldsmem;                       // h A-frag double buffer (2x32 KB)
    char*  xs  = ldsmem + HBUF_BYTES;          // X stage, 64 KB (aliases auf)
    float* auf = (float*)(ldsmem + HBUF_BYTES);

    const int tid = threadIdx.x;
    const int w   = tid >> 6;        // wave: owns n-cols [64w, 64w+64)
    const int ln  = tid & 63;
    const int c   = ln & 15;
    const int q   = ln >> 4;
    const int blk = blockIdx.x;              // 256 tiles of 64 rows
    const int bb  = blk >> 5;                // batch
    const int l0  = (blk & 31) * 64;         // first output row within batch

    int   ncol[4];
    float itau[4];
#pragma unroll
    for (int nl = 0; nl < 4; ++nl) {
        ncol[nl] = (w * 4 + nl) * 16 + c;
        itau[nl] = 1.0f / tau[ncol[nl]];
    }

    const float* xb = x + (long)bb * (Ldim * Ddim);
    const f32x4 zf = {0.f, 0.f, 0.f, 0.f};

    // ---- cooperative X stage: 64 chunk-halves, flat = mt*16 + kt*2 + h (mt<4) ----
    // lane ln of chunk (mt,kt,h) holds x[l0-7+mt*16+(ln&15)][kt*32+(ln>>4)*8+h*4..+4]
    {
        f32x4 sv[16];
#pragma unroll
        for (int it = 0; it < 16; ++it) {
            int flat = it * 4 + w;
            int mt = flat >> 4, kt = (flat >> 1) & 7, hh = flat & 1;
            int lrow = l0 - 7 + mt * 16 + c;          // <= l0+56 < Ldim always
            int rcl  = lrow < 0 ? 0 : lrow;
            const f32x4* g = (const f32x4*)(xb + (long)rcl * Ddim + kt * 32 + q * 8 + hh * 4);
            f32x4 v = *g;
            sv[it] = (lrow >= 0) ? v : zf;
        }
#pragma unroll
        for (int it = 0; it < 16; ++it)
            *(f32x4*)(xs + (it * 4 + w) * 1024 + ln * 16) = sv[it];
    }

    // phase-1 weight dbuf
    bf16x8 w0[4], w1[4];
    auto loadW = [&](bf16x8 (&wb)[4], int kt) {
#pragma unroll
        for (int nl = 0; nl < 4; ++nl)
            wb[nl] = winsw[(kt * 16 + 4 * w + nl) * 64 + ln];
    };
    loadW(w0, 0); loadW(w1, 1);

    // ------------- phase 1: au = X_window @ W_in + bias (C layout) -------------
    // 5 mt tiles cover au rows 0..79 (abs l0-7 .. l0+72); rows 0..70 used.
    f32x4 au[5][4];
#pragma unroll
    for (int nl = 0; nl < 4; ++nl) {
        float bv = bias[ncol[nl]];
#pragma unroll
        for (int mt = 0; mt < 5; ++mt) {
            f32x4 t = {bv, bv, bv, bv};
            au[mt][nl] = t;
        }
    }

    // mt=4 tail rows (l0+57+c), depth-2 global pipeline
    auto loadXg = [&](f32x4 (&buf)[2], int kt) {
        int  lrow = l0 + 57 + c;
        bool ok   = lrow < Ldim;
        const f32x4* p = (const f32x4*)(xb + (long)lrow * Ddim + kt * 32 + q * 8);
        buf[0] = ok ? p[0] : zf;
        buf[1] = ok ? p[1] : zf;
    };
    auto step1 = [&](int kt, const f32x4 (&xg)[2], const bf16x8 (&wb)[4]) {
        bf16x8 aF[5];
#pragma unroll
        for (int mt = 0; mt < 4; ++mt) {
            f32x4 b0 = *(const f32x4*)(xs + (mt * 16 + kt * 2 + 0) * 1024 + ln * 16);
            f32x4 b1 = *(const f32x4*)(xs + (mt * 16 + kt * 2 + 1) * 1024 + ln * 16);
#pragma unroll
            for (int jj = 0; jj < 4; ++jj) {
                aF[mt][jj]     = (bf16_t)b0[jj];
                aF[mt][jj + 4] = (bf16_t)b1[jj];
            }
        }
#pragma unroll
        for (int jj = 0; jj < 4; ++jj) {
            aF[4][jj]     = (bf16_t)xg[0][jj];
            aF[4][jj + 4] = (bf16_t)xg[1][jj];
        }
#pragma unroll
        for (int nl = 0; nl < 4; ++nl)
#pragma unroll
            for (int mt = 0; mt < 5; ++mt)
                au[mt][nl] = __builtin_amdgcn_mfma_f32_16x16x32_bf16(
                    aF[mt], wb[nl], au[mt][nl], 0, 0, 0);
    };

    {
        f32x4 xg0[2], xg1[2];
        loadXg(xg0, 0);
        __syncthreads();   // staged X visible to all waves
        loadXg(xg1, 1);
#pragma unroll 1
        for (int kk = 0; kk < 4; ++kk) {
            step1(2 * kk, xg0, w0);
            if (kk < 3) { loadXg(xg0, 2 * kk + 2); loadW(w0, 2 * kk + 2); }
            step1(2 * kk + 1, xg1, w1);
            if (kk < 3) { loadXg(xg1, 2 * kk + 3); loadW(w1, 2 * kk + 3); }
        }
    }

    __syncthreads();   // all waves done reading xs before auf overwrites it

    // spill au -> LDS (wave-private column stripe; rows 0..70 used)
#pragma unroll
    for (int mt = 0; mt < 5; ++mt)
#pragma unroll
        for (int nl = 0; nl < 4; ++nl)
#pragma unroll
            for (int r = 0; r < 4; ++r) {
                int row = mt * 16 + q * 4 + r;
                if (row < AU_ROWS)
                    auf[row * AU_STRIDE + ncol[nl]] = au[mt][nl][r];
            }

    // W B-fragments, register resident (128 VGPRs) — hoisted so their L2
    // latency hides under h-init + scatter + prefetch + barrier below
    bf16x8 bfr[8][4];
#pragma unroll
    for (int kt = 0; kt < 8; ++kt)
#pragma unroll
        for (int nl = 0; nl < 4; ++nl)
            bfr[kt][nl] = wsw[(kt * 16 + 4 * w + nl) * 64 + ln];

    // h init: h_1 = itau * relu(u at window row m), m = mt*16 + 4q + r (0..63)
    f32x4 h[4][4];
#pragma unroll
    for (int mt = 0; mt < 4; ++mt)
#pragma unroll
        for (int nl = 0; nl < 4; ++nl)
#pragma unroll
            for (int r = 0; r < 4; ++r)
                h[mt][nl][r] = itau[nl] * fmaxf(au[mt][nl][r], 0.0f);

    // per-lane scatter byte offsets (t-invariant), bank-conflict-free perm
    int offn[4];
#pragma unroll
    for (int nl = 0; nl < 4; ++nl) {
        int kk = ncol[nl];
        offn[nl] = (kk >> 5) * 1024 + ((kk >> 3) & 3) * 64 + q * 16 + (kk & 7) * 2;
    }
    const int permln = (((ln & 3) << 4) | ((ln >> 4) << 2) | ((ln >> 2) & 3)) * 16;

    // initial scatter of h into buf 0
#pragma unroll
    for (int mt = 0; mt < 4; ++mt)
#pragma unroll
        for (int nl = 0; nl < 4; ++nl)
#pragma unroll
            for (int r = 0; r < 4; ++r)
                *(bf16_t*)(hb + mt * 8192 + r * 256 + offn[nl]) =
                    (bf16_t)h[mt][nl][r];

    // t-invariant u-read base pointers (bumped += AU_STRIDE per step);
    // read immediates (mt*16+r)*AU_STRIDE*4 <= 52.7 KB < 64 KB offset field.
    const float* ub[4];
#pragma unroll
    for (int nl = 0; nl < 4; ++nl)
        ub[nl] = auf + (4 * q + 1) * AU_STRIDE + ncol[nl];

    // prefetch u for t=1 (wave-self-contained: own wave's lanes wrote these
    // rows/cols of auf -> no barrier needed, lgkm orders)
    float up[4][4][4];
#pragma unroll
    for (int mt = 0; mt < 4; ++mt)
#pragma unroll
        for (int nl = 0; nl < 4; ++nl)
#pragma unroll
            for (int r = 0; r < 4; ++r)
                up[mt][nl][r] = ub[nl][(mt * 16 + r) * AU_STRIDE];

    __syncthreads();

    int cur = 0;
#pragma unroll 1
    for (int t = 1; t < 8; ++t) {
        char* pc = hb + cur * 32768 + permln;   // gather base (+imm)
        char* pn = hb + (cur ^ 1) * 32768;      // scatter base (+offn+imm)
#pragma unroll
        for (int mt = 0; mt < 4; ++mt) {
            f32x4 acc[4];
#pragma unroll
            for (int nl = 0; nl < 4; ++nl) {
                f32x4 a = {up[mt][nl][0], up[mt][nl][1], up[mt][nl][2], up[mt][nl][3]};
                acc[nl] = a;
            }
            // after last mt's up consumed: bump bases, prefetch next step's u
            if (mt == 3 && t < 7) {
#pragma unroll
                for (int nl = 0; nl < 4; ++nl) ub[nl] += AU_STRIDE;
#pragma unroll
                for (int m2 = 0; m2 < 4; ++m2)
#pragma unroll
                    for (int nl = 0; nl < 4; ++nl)
#pragma unroll
                        for (int r = 0; r < 4; ++r)
                            up[m2][nl][r] = ub[nl][(m2 * 16 + r) * AU_STRIDE];
            }
#pragma unroll
            for (int kt = 0; kt < 8; ++kt) {
                bf16x8 aF = *(const bf16x8*)(pc + (mt * 8 + kt) * 1024);
#pragma unroll
                for (int nl = 0; nl < 4; ++nl)
                    acc[nl] = __builtin_amdgcn_mfma_f32_16x16x32_bf16(
                        aF, bfr[kt][nl], acc[nl], 0, 0, 0);
            }
#pragma unroll
            for (int nl = 0; nl < 4; ++nl)
#pragma unroll
                for (int r = 0; r < 4; ++r) {
                    float hh = h[mt][nl][r];
                    float s  = fmaxf(acc[nl][r], 0.0f);
                    hh = hh + itau[nl] * (s - hh);
                    h[mt][nl][r] = hh;
                    if (t < 7)
                        *(bf16_t*)(pn + mt * 8192 + r * 256 + offn[nl]) = (bf16_t)hh;
                }
        }
        if (t < 7) __syncthreads();
        cur ^= 1;
    }

    // ------------- epilogue: 64 rows -------------
    float* ob = out + ((long)bb * Ldim + l0) * Ddim;
#pragma unroll
    for (int mt = 0; mt < 4; ++mt)
#pragma unroll
        for (int nl = 0; nl < 4; ++nl)
#pragma unroll
            for (int r = 0; r < 4; ++r)
                ob[(mt * 16 + 4 * q + r) * Ddim + ncol[nl]] = h[mt][nl][r];
}

extern "C" void kernel_launch(void* const* d_in, const int* in_sizes, int n_in,
                              void* d_out, int out_size, void* d_ws, size_t ws_size,
                              hipStream_t stream) {
    const float* x            = (const float*)d_in[0];
    const float* weight       = (const float*)d_in[1];
    const float* input_weight = (const float*)d_in[2];
    const float* bias         = (const float*)d_in[3];
    const float* tau          = (const float*)d_in[4];
    (void)in_sizes; (void)n_in; (void)out_size; (void)ws_size;

    bf16_t* wsw   = (bf16_t*)d_ws;
    bf16_t* winsw = wsw + 65536;

    static bool attr_set = false;
    if (!attr_set) {
        (void)hipFuncSetAttribute((const void*)rnn_kernel,
                                  hipFuncAttributeMaxDynamicSharedMemorySize,
                                  LDS_TOTAL);
        attr_set = true;
    }

    swz_kernel<<<16, 256, 0, stream>>>(weight, input_weight, wsw, winsw);
    rnn_kernel<<<256, 256, LDS_TOTAL, stream>>>(x, bias, tau,
                                                (const bf16x8*)wsw,
                                                (const bf16x8*)winsw,
                                                (float*)d_out);
}

// Round 11
// 104.623 us; speedup vs baseline: 1.1012x; 1.1012x over previous
//
#include <hip/hip_runtime.h>

typedef __bf16 bf16_t;
typedef __bf16 bf16x8 __attribute__((ext_vector_type(8)));
typedef float  f32x4  __attribute__((ext_vector_type(4)));

#define Ldim 2048
#define Ddim 256

// Build frag-major (B-operand) bf16 copies of weight and input_weight.
// Frag element ((kt*16+nt)*64 + lane)*8 + j  =  W[k=kt*32+(lane>>4)*8+j][n=nt*16+(lane&15)]
__global__ void swz_kernel(const float* __restrict__ w,
                           const float* __restrict__ win,
                           bf16_t* __restrict__ wsw,
                           bf16_t* __restrict__ winsw) {
    int mat = blockIdx.x >> 3, kt = blockIdx.x & 7;
    const float* src = mat ? win : w;
    bf16_t*      dst = mat ? winsw : wsw;
    int ln = threadIdx.x & 63, g = threadIdx.x >> 6;
    int c = ln & 15, q = ln >> 4;
#pragma unroll
    for (int i = 0; i < 4; ++i) {
        int nt = g + 4 * i;
        bf16x8 v;
#pragma unroll
        for (int j = 0; j < 8; ++j)
            v[j] = (bf16_t)src[(kt * 32 + q * 8 + j) * Ddim + nt * 16 + c];
        *(bf16x8*)&dst[((kt * 16 + nt) * 64 + ln) * 8] = v;
    }
}

#define AU_STRIDE 258   // f32; 4-row step = 1032 B -> 2-way bank alias (free)
#define AU_ROWS   40
#define AU_BYTES  (AU_ROWS * AU_STRIDE * 4)       // 41280
#define HBUF_BYTES 32768                          // [2 buf][2 mt][8 kt][1024]
#define LDS_TOTAL (HBUF_BYTES + AU_BYTES)         // 74048 -> 2 blocks/CU

extern __shared__ char ldsmem[];

// R9 revert (session best, 104.6 us): 32-row tile, 512 blocks = 2 independent
// blocks/CU (R9 vs R10 A/B: 2 blk/CU is worth ~20% — co-resident independent
// blocks cover each other's barrier/gather stall windows). Cooperative
// X-staging, u-register-prefetch, immediate addressing, setprio.
// R11 delta: the next-step u-prefetch is split in halves, each issued at the
// point its up[] buffer dies (after that mt's acc-init) so ~95 cyc of LDS
// reads hide under a full 32-MFMA block instead of clumping (R9 put all 32
// reads before the LAST MFMA block; the tail leaked into the barrier drain).
__global__ __launch_bounds__(256, 2)
void rnn_kernel(const float* __restrict__ x,
                const float* __restrict__ bias,
                const float* __restrict__ tau,
                const bf16x8* __restrict__ wsw,
                const bf16x8* __restrict__ winsw,
                float* __restrict__ out)
{
    char*  hb  = ldsmem;                       // h A-frag double buffer
    char*  xs  = ldsmem + HBUF_BYTES;          // X stage (aliases auf)
    float* auf = (float*)(ldsmem + HBUF_BYTES);

    const int tid = threadIdx.x;
    const int w   = tid >> 6;        // wave: owns n-cols [64w, 64w+64)
    const int ln  = tid & 63;
    const int c   = ln & 15;
    const int q   = ln >> 4;
    const int tile = blockIdx.x;             // 512 tiles of 32 rows
    const int bb  = tile >> 6;               // batch
    const int l0  = (tile & 63) * 32;        // first output row within batch

    int   ncol[4];
    float itau[4];
#pragma unroll
    for (int nl = 0; nl < 4; ++nl) {
        ncol[nl] = (w * 4 + nl) * 16 + c;
        itau[nl] = 1.0f / tau[ncol[nl]];
    }

    const float* xb = x + (long)bb * (Ldim * Ddim);
    const f32x4 zf = {0.f, 0.f, 0.f, 0.f};

    // ---- cooperative X stage: chunk-half flat = mt*16 + kt*2 + h (mt in {0,1}) ----
    // lane ln of chunk (mt,kt,h) holds x[l0-7+mt*16+(ln&15)][kt*32+(ln>>4)*8+h*4 ..+4]
    f32x4 sv[8];
    int   sfl[8];
#pragma unroll
    for (int it = 0; it < 8; ++it) {
        int flat = it * 4 + w;
        sfl[it] = flat;
        int mt = flat >> 4, kt = (flat >> 1) & 7, hh = flat & 1;
        int lrow = l0 - 7 + mt * 16 + c;               // <= l0+24, >= -7
        int rcl  = lrow < 0 ? 0 : lrow;
        const f32x4* g = (const f32x4*)(xb + (long)rcl * Ddim + kt * 32 + q * 8 + hh * 4);
        f32x4 v = *g;
        sv[it] = (lrow >= 0) ? v : zf;
    }

    // phase-1 weight dbuf: issue first two kt AFTER sv loads (counted vmcnt lets
    // the ds_writes below wait only on sv, with winsw still in flight)
    bf16x8 w0[4], w1[4];
    auto loadW = [&](bf16x8 (&wb)[4], int kt) {
#pragma unroll
        for (int nl = 0; nl < 4; ++nl)
            wb[nl] = winsw[(kt * 16 + 4 * w + nl) * 64 + ln];
    };
    loadW(w0, 0); loadW(w1, 1);

#pragma unroll
    for (int it = 0; it < 8; ++it)
        *(f32x4*)(xs + sfl[it] * 1024 + ln * 16) = sv[it];

    // ------------- phase 1: au = X_window @ W_in + bias (C layout) -------------
    f32x4 au[3][4];
#pragma unroll
    for (int nl = 0; nl < 4; ++nl) {
        float bv = bias[ncol[nl]];
#pragma unroll
        for (int mt = 0; mt < 3; ++mt) {
            f32x4 t = {bv, bv, bv, bv};
            au[mt][nl] = t;
        }
    }

    // mt=2 tail rows (l0+25+c), depth-2 global pipeline
    auto loadXg = [&](f32x4 (&buf)[2], int kt) {
        int  lrow = l0 + 25 + c;
        bool ok   = lrow < Ldim;
        const f32x4* p = (const f32x4*)(xb + (long)lrow * Ddim + kt * 32 + q * 8);
        buf[0] = ok ? p[0] : zf;
        buf[1] = ok ? p[1] : zf;
    };
    auto step1 = [&](int kt, const f32x4 (&xg)[2], const bf16x8 (&wb)[4]) {
        bf16x8 aF[3];
#pragma unroll
        for (int mt = 0; mt < 2; ++mt) {
            f32x4 b0 = *(const f32x4*)(xs + (mt * 16 + kt * 2 + 0) * 1024 + ln * 16);
            f32x4 b1 = *(const f32x4*)(xs + (mt * 16 + kt * 2 + 1) * 1024 + ln * 16);
#pragma unroll
            for (int jj = 0; jj < 4; ++jj) {
                aF[mt][jj]     = (bf16_t)b0[jj];
                aF[mt][jj + 4] = (bf16_t)b1[jj];
            }
        }
#pragma unroll
        for (int jj = 0; jj < 4; ++jj) {
            aF[2][jj]     = (bf16_t)xg[0][jj];
            aF[2][jj + 4] = (bf16_t)xg[1][jj];
        }
#pragma unroll
        for (int nl = 0; nl < 4; ++nl)
#pragma unroll
            for (int mt = 0; mt < 3; ++mt)
                au[mt][nl] = __builtin_amdgcn_mfma_f32_16x16x32_bf16(
                    aF[mt], wb[nl], au[mt][nl], 0, 0, 0);
    };

    {
        f32x4 xg0[2], xg1[2];
        loadXg(xg0, 0);
        __syncthreads();   // staged X visible to all waves
        loadXg(xg1, 1);
#pragma unroll 1
        for (int kk = 0; kk < 4; ++kk) {
            step1(2 * kk, xg0, w0);
            if (kk < 3) { loadXg(xg0, 2 * kk + 2); loadW(w0, 2 * kk + 2); }
            step1(2 * kk + 1, xg1, w1);
            if (kk < 3) { loadXg(xg1, 2 * kk + 3); loadW(w1, 2 * kk + 3); }
        }
    }

    __syncthreads();   // all waves done reading xs before auf overwrites it

    // spill au -> LDS (wave-private column stripe; rows 0..38 used)
#pragma unroll
    for (int mt = 0; mt < 3; ++mt)
#pragma unroll
        for (int nl = 0; nl < 4; ++nl)
#pragma unroll
            for (int r = 0; r < 4; ++r) {
                int row = mt * 16 + q * 4 + r;
                if (row < 39)
                    auf[row * AU_STRIDE + ncol[nl]] = au[mt][nl][r];
            }

    // h init: h_1 = itau * relu(u at window row m), m = mt*16 + q*4 + r (0..31)
    f32x4 h[2][4];
#pragma unroll
    for (int mt = 0; mt < 2; ++mt)
#pragma unroll
        for (int nl = 0; nl < 4; ++nl)
#pragma unroll
            for (int r = 0; r < 4; ++r)
                h[mt][nl][r] = itau[nl] * fmaxf(au[mt][nl][r], 0.0f);

    // ------------- phase 2: 7 more recurrence steps -------------
    bf16x8 bfr[8][4];   // W B-fragments, register resident (128 VGPRs)
#pragma unroll
    for (int kt = 0; kt < 8; ++kt)
#pragma unroll
        for (int nl = 0; nl < 4; ++nl)
            bfr[kt][nl] = wsw[(kt * 16 + 4 * w + nl) * 64 + ln];

    // per-lane scatter byte offsets (t-invariant), bank-conflict-free perm
    int offn[4];
#pragma unroll
    for (int nl = 0; nl < 4; ++nl) {
        int kk = ncol[nl];
        offn[nl] = (kk >> 5) * 1024 + ((kk >> 3) & 3) * 64 + q * 16 + (kk & 7) * 2;
    }
    const int permln = (((ln & 3) << 4) | ((ln >> 4) << 2) | ((ln >> 2) & 3)) * 16;

    // initial scatter of h into buf 0
#pragma unroll
    for (int mt = 0; mt < 2; ++mt)
#pragma unroll
        for (int nl = 0; nl < 4; ++nl)
#pragma unroll
            for (int r = 0; r < 4; ++r)
                *(bf16_t*)(hb + mt * 8192 + r * 256 + offn[nl]) =
                    (bf16_t)h[mt][nl][r];

    // t-invariant u-read base pointers (bumped += AU_STRIDE per step);
    // reads use compile-time immediates (mt*16+r)*AU_STRIDE*4 <= 19.6 KB.
    const float* ub[4];
#pragma unroll
    for (int nl = 0; nl < 4; ++nl)
        ub[nl] = auf + (4 * q + 1) * AU_STRIDE + ncol[nl];

    // prefetch u for t=1 (wave-self-contained: this wave's lanes wrote these
    // rows/cols of auf -> no barrier needed, lgkm orders)
    float up[2][4][4];
#pragma unroll
    for (int mt = 0; mt < 2; ++mt)
#pragma unroll
        for (int nl = 0; nl < 4; ++nl)
#pragma unroll
            for (int r = 0; r < 4; ++r)
                up[mt][nl][r] = ub[nl][(mt * 16 + r) * AU_STRIDE];

    __syncthreads();

    int cur = 0;
#pragma unroll 1
    for (int t = 1; t < 8; ++t) {
        char* pc = hb + cur * 16384 + permln;   // gather base (+imm)
        char* pn = hb + (cur ^ 1) * 16384;      // scatter base (+offn+imm)

        // ---------------- mt = 0 ----------------
        f32x4 acc0[4];
#pragma unroll
        for (int nl = 0; nl < 4; ++nl) {
            f32x4 a = {up[0][nl][0], up[0][nl][1], up[0][nl][2], up[0][nl][3]};
            acc0[nl] = a;
        }
        // up[0] dead: bump bases, refill half A under mt0's MFMA block
        if (t < 7) {
#pragma unroll
            for (int nl = 0; nl < 4; ++nl) ub[nl] += AU_STRIDE;
#pragma unroll
            for (int nl = 0; nl < 4; ++nl)
#pragma unroll
                for (int r = 0; r < 4; ++r)
                    up[0][nl][r] = ub[nl][r * AU_STRIDE];
        }
        __builtin_amdgcn_s_setprio(1);
#pragma unroll
        for (int kt = 0; kt < 8; ++kt) {
            bf16x8 aF = *(const bf16x8*)(pc + kt * 1024);
#pragma unroll
            for (int nl = 0; nl < 4; ++nl)
                acc0[nl] = __builtin_amdgcn_mfma_f32_16x16x32_bf16(
                    aF, bfr[kt][nl], acc0[nl], 0, 0, 0);
        }
        __builtin_amdgcn_s_setprio(0);
#pragma unroll
        for (int nl = 0; nl < 4; ++nl)
#pragma unroll
            for (int r = 0; r < 4; ++r) {
                float hh = h[0][nl][r];
                float s  = fmaxf(acc0[nl][r], 0.0f);
                hh = hh + itau[nl] * (s - hh);
                h[0][nl][r] = hh;
                if (t < 7)
                    *(bf16_t*)(pn + r * 256 + offn[nl]) = (bf16_t)hh;
            }

        // ---------------- mt = 1 ----------------
        f32x4 acc1[4];
#pragma unroll
        for (int nl = 0; nl < 4; ++nl) {
            f32x4 a = {up[1][nl][0], up[1][nl][1], up[1][nl][2], up[1][nl][3]};
            acc1[nl] = a;
        }
        // up[1] dead: refill half B under mt1's MFMA block (bases already bumped)
        if (t < 7) {
#pragma unroll
            for (int nl = 0; nl < 4; ++nl)
#pragma unroll
                for (int r = 0; r < 4; ++r)
                    up[1][nl][r] = ub[nl][(16 + r) * AU_STRIDE];
        }
        __builtin_amdgcn_s_setprio(1);
#pragma unroll
        for (int kt = 0; kt < 8; ++kt) {
            bf16x8 aF = *(const bf16x8*)(pc + (8 + kt) * 1024);
#pragma unroll
            for (int nl = 0; nl < 4; ++nl)
                acc1[nl] = __builtin_amdgcn_mfma_f32_16x16x32_bf16(
                    aF, bfr[kt][nl], acc1[nl], 0, 0, 0);
        }
        __builtin_amdgcn_s_setprio(0);
#pragma unroll
        for (int nl = 0; nl < 4; ++nl)
#pragma unroll
            for (int r = 0; r < 4; ++r) {
                float hh = h[1][nl][r];
                float s  = fmaxf(acc1[nl][r], 0.0f);
                hh = hh + itau[nl] * (s - hh);
                h[1][nl][r] = hh;
                if (t < 7)
                    *(bf16_t*)(pn + 8192 + r * 256 + offn[nl]) = (bf16_t)hh;
            }

        if (t < 7) __syncthreads();
        cur ^= 1;
    }

    // ------------- epilogue -------------
    float* ob = out + ((long)bb * Ldim + l0) * Ddim;
#pragma unroll
    for (int mt = 0; mt < 2; ++mt)
#pragma unroll
        for (int nl = 0; nl < 4; ++nl)
#pragma unroll
            for (int r = 0; r < 4; ++r)
                ob[(mt * 16 + 4 * q + r) * Ddim + ncol[nl]] = h[mt][nl][r];
}

extern "C" void kernel_launch(void* const* d_in, const int* in_sizes, int n_in,
                              void* d_out, int out_size, void* d_ws, size_t ws_size,
                              hipStream_t stream) {
    const float* x            = (const float*)d_in[0];
    const float* weight       = (const float*)d_in[1];
    const float* input_weight = (const float*)d_in[2];
    const float* bias         = (const float*)d_in[3];
    const float* tau          = (const float*)d_in[4];
    (void)in_sizes; (void)n_in; (void)out_size; (void)ws_size;

    bf16_t* wsw   = (bf16_t*)d_ws;
    bf16_t* winsw = wsw + 65536;

    static bool attr_set = false;
    if (!attr_set) {
        (void)hipFuncSetAttribute((const void*)rnn_kernel,
                                  hipFuncAttributeMaxDynamicSharedMemorySize,
                                  LDS_TOTAL);
        attr_set = true;
    }

    swz_kernel<<<16, 256, 0, stream>>>(weight, input_weight, wsw, winsw);
    rnn_kernel<<<512, 256, LDS_TOTAL, stream>>>(x, bias, tau,
                                                (const bf16x8*)wsw,
                                                (const bf16x8*)winsw,
                                                (float*)d_out);
}